// Round 1
// baseline (1497.580 us; speedup 1.0000x reference)
//
#include <hip/hip_runtime.h>
#include <math.h>

// H[i,j] = max_k ( |W[i,k]| + |W[j,k]| ), W: N x K fp32, H: N x N fp32.
// Tropical gram matrix -> pure VALU problem (no MFMA for max-plus).
// Strategy: symmetric upper-tri 64x64 tiles, k-major LDS, ds_read_b128
// fragments, v_max3 pairing over k, async global->reg prefetch.

constexpr int N  = 2048;
constexpr int K  = 10000;
constexpr int BT = 64;                  // output tile dim
constexpr int BK = 32;                  // k-step
constexpr int NT = N / BT;              // 32 tiles per dim
constexpr int NBLK = NT * (NT + 1) / 2; // 528 upper-tri blocks
constexpr int NSTEP = (K + BK - 1) / BK; // 313 (last step zero-padded)

__global__ __launch_bounds__(256, 4)
void tropical_gram_kernel(const float* __restrict__ W, float* __restrict__ H) {
    // k-major LDS tiles: As[kk][row] so fragment load = ds_read_b128
    __shared__ float As[BK][BT];
    __shared__ float Bs[BK][BT];

    const int tid = threadIdx.x;

    // decode upper-triangular (bi <= bj) block pair from linear index
    int t = blockIdx.x;
    int bi = 0;
    while (t >= NT - bi) { t -= NT - bi; ++bi; }
    const int bj = bi + t;

    const int i0 = bi * BT;
    const int j0 = bj * BT;

    // ---- staging mapping: thread loads 8 consecutive k of one row, per tile
    const int srow = tid & 63;   // 0..63 (row within tile)
    const int kq   = tid >> 6;   // 0..3, wave-uniform (8 k's each)

    const float* rowi = W + (size_t)(i0 + srow) * K;
    const float* rowj = W + (size_t)(j0 + srow) * K;

    // ---- compute mapping: 4x4 register tile per thread
    const int tx = tid & 15;     // column group
    const int ty = tid >> 4;     // row group (0..15)
    const int r0 = ty * 4;
    const int c0 = tx * 4;

    float acc[4][4];
#pragma unroll
    for (int m = 0; m < 4; ++m)
#pragma unroll
        for (int n = 0; n < 4; ++n) acc[m][n] = 0.0f;   // all terms >= 0, 0 is identity here

    // prefetch registers (step s+1 issued before compute of step s)
    float4 va0, va1, vb0, vb1;
    auto fetch = [&](int s) {
        const int kbase = s * BK + kq * 8;
        if (kbase < K) {  // K%8==0 -> whole 8-float chunk valid or invalid; wave-uniform
            va0 = *reinterpret_cast<const float4*>(rowi + kbase);
            va1 = *reinterpret_cast<const float4*>(rowi + kbase + 4);
            vb0 = *reinterpret_cast<const float4*>(rowj + kbase);
            vb1 = *reinterpret_cast<const float4*>(rowj + kbase + 4);
        } else {
            va0 = va1 = vb0 = vb1 = make_float4(0.f, 0.f, 0.f, 0.f);
        }
    };
    fetch(0);

    for (int s = 0; s < NSTEP; ++s) {
        __syncthreads();                       // previous compute done, LDS free
        const int kb = kq * 8;
        // transpose-on-write; bank = row%32 -> 2-way aliasing (free)
        As[kb + 0][srow] = fabsf(va0.x); As[kb + 1][srow] = fabsf(va0.y);
        As[kb + 2][srow] = fabsf(va0.z); As[kb + 3][srow] = fabsf(va0.w);
        As[kb + 4][srow] = fabsf(va1.x); As[kb + 5][srow] = fabsf(va1.y);
        As[kb + 6][srow] = fabsf(va1.z); As[kb + 7][srow] = fabsf(va1.w);
        Bs[kb + 0][srow] = fabsf(vb0.x); Bs[kb + 1][srow] = fabsf(vb0.y);
        Bs[kb + 2][srow] = fabsf(vb0.z); Bs[kb + 3][srow] = fabsf(vb0.w);
        Bs[kb + 4][srow] = fabsf(vb1.x); Bs[kb + 5][srow] = fabsf(vb1.y);
        Bs[kb + 6][srow] = fabsf(vb1.z); Bs[kb + 7][srow] = fabsf(vb1.w);
        if (s + 1 < NSTEP) fetch(s + 1);       // issue next-step global loads early
        __syncthreads();                       // LDS tile ready

        // 32 k's: pairs of k feed v_max3(acc, t0, t1)
#pragma unroll
        for (int kk = 0; kk < BK; kk += 2) {
            const float4 A0 = *reinterpret_cast<const float4*>(&As[kk][r0]);
            const float4 A1 = *reinterpret_cast<const float4*>(&As[kk + 1][r0]);
            const float4 B0 = *reinterpret_cast<const float4*>(&Bs[kk][c0]);
            const float4 B1 = *reinterpret_cast<const float4*>(&Bs[kk + 1][c0]);
            const float a0[4] = {A0.x, A0.y, A0.z, A0.w};
            const float a1[4] = {A1.x, A1.y, A1.z, A1.w};
            const float b0[4] = {B0.x, B0.y, B0.z, B0.w};
            const float b1[4] = {B1.x, B1.y, B1.z, B1.w};
#pragma unroll
            for (int m = 0; m < 4; ++m) {
#pragma unroll
                for (int n = 0; n < 4; ++n) {
                    const float t0 = a0[m] + b0[n];
                    const float t1 = a1[m] + b1[n];
                    acc[m][n] = fmaxf(acc[m][n], fmaxf(t0, t1)); // hope: v_max3_f32
                }
            }
        }
    }

    // ---- epilogue: direct tile + mirrored (transposed) tile
#pragma unroll
    for (int m = 0; m < 4; ++m) {
        float4 v = make_float4(acc[m][0], acc[m][1], acc[m][2], acc[m][3]);
        *reinterpret_cast<float4*>(&H[(size_t)(i0 + r0 + m) * N + j0 + c0]) = v;
    }
    if (bi != bj) {
#pragma unroll
        for (int n = 0; n < 4; ++n) {
            float4 v = make_float4(acc[0][n], acc[1][n], acc[2][n], acc[3][n]);
            *reinterpret_cast<float4*>(&H[(size_t)(j0 + c0 + n) * N + i0 + r0]) = v;
        }
    }
}

extern "C" void kernel_launch(void* const* d_in, const int* in_sizes, int n_in,
                              void* d_out, int out_size, void* d_ws, size_t ws_size,
                              hipStream_t stream) {
    const float* W = (const float*)d_in[0];
    float* H = (float*)d_out;
    (void)in_sizes; (void)n_in; (void)d_ws; (void)ws_size; (void)out_size;

    tropical_gram_kernel<<<dim3(NBLK), dim3(256), 0, stream>>>(W, H);
}

// Round 4
// 1178.038 us; speedup vs baseline: 1.2712x; 1.2712x over previous
//
#include <hip/hip_runtime.h>
#include <math.h>

// H[i,j] = max_k ( |W[i,k]| + |W[j,k]| ), W: 2048 x 10000 fp32 (values >= 0).
// Max-plus gram: pure VALU (no MFMA). Round 4: same as round-3 design
// (8x8 per-thread tile as four 4x4 sub-tiles -> all LDS reads <=2-way
// bank-aliased; LDS demand ~85 B/cyc/CU ~= b128 ceiling, balanced vs VALU;
// K-split x4; v_max3 asm; int-bitcast atomicMax merge), but the output
// zero-init is a plain kernel instead of hipMemsetAsync to remove any
// graph-capture risk from the launch path.

constexpr int N  = 2048;
constexpr int K  = 10000;
constexpr int BT = 128;                  // output tile dim
constexpr int BK = 32;                   // k per step
constexpr int NT = N / BT;               // 16
constexpr int NTRI = NT * (NT + 1) / 2;  // 136 upper-tri tiles
constexpr int SPLIT = 4;                 // K-split across blocks
constexpr int KS = K / SPLIT;            // 2500 (exact)
constexpr int NSTEP = (KS + BK - 1) / BK; // 79; ragged tail guarded

__device__ __forceinline__ float max3f(float a, float b, float c) {
    float d;
    asm("v_max3_f32 %0, %1, %2, %3" : "=v"(d) : "v"(a), "v"(b), "v"(c));
    return d;
}

__global__ void zero_out_kernel(float4* __restrict__ p, int n4) {
    const int i = blockIdx.x * blockDim.x + threadIdx.x;
    if (i < n4) p[i] = make_float4(0.f, 0.f, 0.f, 0.f);
}

__global__ __launch_bounds__(256, 2)
void tropical_gram_kernel(const float* __restrict__ W, float* __restrict__ H) {
    __shared__ float As[BK][BT];   // k-major: As[k][row]
    __shared__ float Bs[BK][BT];

    const int tid = threadIdx.x;

    // ---- block decode: split + upper-tri tile (bi <= bj)
    const int bid   = blockIdx.x;
    const int split = bid / NTRI;
    int t = bid % NTRI;
    int bi = 0;
    while (t >= NT - bi) { t -= NT - bi; ++bi; }
    const int bj = bi + t;
    const int i0 = bi * BT, j0 = bj * BT;
    const int kbeg = split * KS;
    const bool diag = (bi == bj);

    // ---- staging mapping: thread stages 16 consecutive k of one row/side
    const int srow = tid & 127;          // row within tile
    const int kh   = tid >> 7;           // 0/1: which 16-k half (wave-uniform)
    const float* rowi = W + (size_t)(i0 + srow) * K + kbeg + kh * 16;
    const float* rowj = W + (size_t)(j0 + srow) * K + kbeg + kh * 16;

    // ---- compute mapping: four 4x4 sub-tiles per thread at (+0,+64)
    const int tx = tid & 15, ty = tid >> 4;
    const int ra = ty * 4, rb = ra + 64;   // row starts
    const int ca = tx * 4, cb = ca + 64;   // col starts

    float acc[8][8];   // m: 0-3 -> ra+m, 4-7 -> rb+(m-4); n likewise ca/cb
#pragma unroll
    for (int m = 0; m < 8; ++m)
#pragma unroll
        for (int n = 0; n < 8; ++n) acc[m][n] = 0.0f;  // all sums >= 0

    // ---- prefetch registers (T14: issue early, LDS-write late)
    float4 va[4], vb[4];
    const float4 z4 = make_float4(0.f, 0.f, 0.f, 0.f);

    auto fetchA = [&](int s) {
#pragma unroll
        for (int q = 0; q < 4; ++q) {
            const int kg = kbeg + kh * 16 + s * BK + q * 4;  // global k
            va[q] = (kg < K) ? *reinterpret_cast<const float4*>(rowi + s * BK + q * 4) : z4;
        }
    };
    auto fetchB = [&](int s) {
#pragma unroll
        for (int q = 0; q < 4; ++q) {
            const int kg = kbeg + kh * 16 + s * BK + q * 4;
            vb[q] = (kg < K) ? *reinterpret_cast<const float4*>(rowj + s * BK + q * 4) : z4;
        }
    };

    fetchA(0);
    if (!diag) fetchB(0);

    // diagonal blocks read B fragments from As (half the staging)
    const float (*Bsrc)[BT] = diag ? As : Bs;

    for (int s = 0; s < NSTEP; ++s) {
        __syncthreads();                 // previous compute done with LDS
        // transposed LDS write: bank = srow%32 across lanes -> 2-way (free)
#pragma unroll
        for (int q = 0; q < 4; ++q) {
            const int kb = kh * 16 + q * 4;
            As[kb + 0][srow] = fabsf(va[q].x);
            As[kb + 1][srow] = fabsf(va[q].y);
            As[kb + 2][srow] = fabsf(va[q].z);
            As[kb + 3][srow] = fabsf(va[q].w);
        }
        if (!diag) {
#pragma unroll
            for (int q = 0; q < 4; ++q) {
                const int kb = kh * 16 + q * 4;
                Bs[kb + 0][srow] = fabsf(vb[q].x);
                Bs[kb + 1][srow] = fabsf(vb[q].y);
                Bs[kb + 2][srow] = fabsf(vb[q].z);
                Bs[kb + 3][srow] = fabsf(vb[q].w);
            }
        }
        if (s + 1 < NSTEP) {             // issue next-step loads under compute
            fetchA(s + 1);
            if (!diag) fetchB(s + 1);
        }
        __syncthreads();                 // LDS tile ready

#pragma unroll 2
        for (int kk = 0; kk < BK; kk += 2) {
            // all reads stride-16B across lanes -> <=2-way bank aliasing
            const float4 A0a = *reinterpret_cast<const float4*>(&As[kk][ra]);
            const float4 A0b = *reinterpret_cast<const float4*>(&As[kk][rb]);
            const float4 A1a = *reinterpret_cast<const float4*>(&As[kk + 1][ra]);
            const float4 A1b = *reinterpret_cast<const float4*>(&As[kk + 1][rb]);
            const float4 B0a = *reinterpret_cast<const float4*>(&Bsrc[kk][ca]);
            const float4 B0b = *reinterpret_cast<const float4*>(&Bsrc[kk][cb]);
            const float4 B1a = *reinterpret_cast<const float4*>(&Bsrc[kk + 1][ca]);
            const float4 B1b = *reinterpret_cast<const float4*>(&Bsrc[kk + 1][cb]);
            const float a0[8] = {A0a.x, A0a.y, A0a.z, A0a.w, A0b.x, A0b.y, A0b.z, A0b.w};
            const float a1[8] = {A1a.x, A1a.y, A1a.z, A1a.w, A1b.x, A1b.y, A1b.z, A1b.w};
            const float b0[8] = {B0a.x, B0a.y, B0a.z, B0a.w, B0b.x, B0b.y, B0b.z, B0b.w};
            const float b1[8] = {B1a.x, B1a.y, B1a.z, B1a.w, B1b.x, B1b.y, B1b.z, B1b.w};
#pragma unroll
            for (int m = 0; m < 8; ++m) {
#pragma unroll
                for (int n = 0; n < 8; ++n) {
                    const float t0 = a0[m] + b0[n];
                    const float t1 = a1[m] + b1[n];
                    acc[m][n] = max3f(acc[m][n], t0, t1);
                }
            }
        }
    }

    // ---- epilogue: int-bitcast atomicMax merges the K-splits
    int* Hi = (int*)H;
#pragma unroll
    for (int m = 0; m < 8; ++m) {
        const int r = (m < 4) ? (ra + m) : (rb + m - 4);
#pragma unroll
        for (int n = 0; n < 8; ++n) {
            const int c = (n < 4) ? (ca + n) : (cb + n - 4);
            atomicMax(&Hi[(size_t)(i0 + r) * N + j0 + c], __float_as_int(acc[m][n]));
        }
    }
    if (!diag) {
#pragma unroll
        for (int m = 0; m < 8; ++m) {
            const int r = (m < 4) ? (ra + m) : (rb + m - 4);
#pragma unroll
            for (int n = 0; n < 8; ++n) {
                const int c = (n < 4) ? (ca + n) : (cb + n - 4);
                atomicMax(&Hi[(size_t)(j0 + c) * N + i0 + r], __float_as_int(acc[m][n]));
            }
        }
    }
}

extern "C" void kernel_launch(void* const* d_in, const int* in_sizes, int n_in,
                              void* d_out, int out_size, void* d_ws, size_t ws_size,
                              hipStream_t stream) {
    const float* W = (const float*)d_in[0];
    float* H = (float*)d_out;
    (void)in_sizes; (void)n_in; (void)d_ws; (void)ws_size; (void)out_size;

    // zero-init below any result so atomicMax merges cleanly (output is
    // re-poisoned to 0xAA before every timed call -> must zero every call)
    const int n4 = N * N / 4;
    zero_out_kernel<<<(n4 + 255) / 256, 256, 0, stream>>>((float4*)H, n4);
    tropical_gram_kernel<<<dim3(NTRI * SPLIT), dim3(256), 0, stream>>>(W, H);
}